// Round 5
// baseline (635.322 us; speedup 1.0000x reference)
//
#include <hip/hip_runtime.h>

typedef unsigned short u16;
typedef unsigned int   u32;
typedef u16   u16x4 __attribute__((ext_vector_type(4)));
typedef u16   u16x8 __attribute__((ext_vector_type(8)));
typedef short s16x8 __attribute__((ext_vector_type(8)));
typedef float f32x4 __attribute__((ext_vector_type(4)));

// ---------- bf16 helpers (bit-level, RNE) ----------
__device__ __forceinline__ float bf2f(u16 u) {
    u32 x = ((u32)u) << 16;
    return __builtin_bit_cast(float, x);
}
__device__ __forceinline__ u16 f2bf(float f) {
    u32 u = __builtin_bit_cast(u32, f);
    u32 r = u + 0x7FFFu + ((u >> 16) & 1u);
    return (u16)(r >> 16);
}

// async global->LDS, 16B per lane; lds dest is wave-uniform base (HW: base + lane*16)
__device__ __forceinline__ void gload16(const u16* g, u16* lds) {
    __builtin_amdgcn_global_load_lds((const __attribute__((address_space(1))) void*)g,
                                     (__attribute__((address_space(3))) void*)lds, 16, 0, 0);
}

// ---------- sizes ----------
#define TOT   16384      // BS*N nodes
#define HID   512
#define NRELS 8
#define NB    4
#define EDGES 262144
#define INDIM 3072
#define NOUT  128
#define NGRAPH 16
#define NODESPER 1024
#define KSPLIT 4         // ELMo split-K factor
#define NBINS  (TOT * NRELS)   // 131072 (dst, rel) bins
#define KAGG   (NRELS * HID)   // 4096

// workspace layout (16B aligned)
#define OFF_XB      ((size_t)0)                    // u16 [16384][512]    16,777,216 B
#define OFF_AGG     (OFF_XB + 16777216)            // u16 [16384][4096]  134,217,728 B (also ELMo f32 partials [4][16384][256] = 67 MB, dead before AGG live)
#define OFF_WST     (OFF_AGG + 134217728)          // u16 [512][4096]      4,194,304 B
#define OFF_WET     (OFF_WST + 4194304)            // u16 [256][3072]      1,572,864 B
#define OFF_CNT2    (OFF_WET + 1572864)            // int [131072]           524,288 B
#define OFF_ROWPTR2 (OFF_CNT2 + 524288)            // int [131073] (+pad)    524,304 B
#define OFF_CURSOR2 (OFF_ROWPTR2 + 524304)         // int [131072]           524,288 B
#define OFF_ESRC    (OFF_CURSOR2 + 524288)         // int [262144]         1,048,576 B
#define OFF_ENORM   (OFF_ESRC + 1048576)           // float [262144]       1,048,576 B
#define OFF_PART    (OFF_ENORM + 1048576)          // float [256][512]       524,288 B

// ---------- prep: WstackT[n][r*512+i] = sum_b comp[r,b] * V[b][i][n]  (bf16, LDS transpose) ----------
__global__ __launch_bounds__(256) void k_prep_wstack(const float* __restrict__ comp,
                                                     const float* __restrict__ V,
                                                     u16* __restrict__ WT) {
    __shared__ float tile[64][65];
    const int i0 = blockIdx.x * 64, n0 = blockIdx.y * 64, r = blockIdx.z;
    const float c0 = comp[r * 4], c1 = comp[r * 4 + 1], c2 = comp[r * 4 + 2], c3 = comp[r * 4 + 3];
    const int tn = threadIdx.x & 63;   // n fast -> coalesced V reads
    const int ti = threadIdx.x >> 6;
#pragma unroll
    for (int q = 0; q < 16; ++q) {
        int i = ti + q * 4;
        const float* vp = V + (size_t)(i0 + i) * 512 + n0 + tn;
        tile[i][tn] = c0 * vp[0] + c1 * vp[262144] + c2 * vp[2 * 262144] + c3 * vp[3 * 262144];
    }
    __syncthreads();
    const int kk = threadIdx.x & 63;   // i fast -> coalesced WT writes
#pragma unroll
    for (int q = 0; q < 16; ++q) {
        int n = (threadIdx.x >> 6) + q * 4;
        WT[(size_t)(n0 + n) * KAGG + r * 512 + i0 + kk] = f2bf(tile[kk][n]);
    }
}

// ---------- prep: WelmoT[n][k] = W_elmo[k][n] (LDS transpose) ----------
__global__ __launch_bounds__(256) void k_prep_welmo(const float* __restrict__ W,
                                                    u16* __restrict__ WT) {
    __shared__ float tile[64][65];
    const int k0 = blockIdx.x * 64, n0 = blockIdx.y * 64;
    const int tn = threadIdx.x & 63;
    const int tk = threadIdx.x >> 6;
#pragma unroll
    for (int i = 0; i < 16; ++i) {
        int k = tk + i * 4;
        tile[k][tn] = W[(size_t)(k0 + k) * 256 + n0 + tn];
    }
    __syncthreads();
    const int kk = threadIdx.x & 63;
#pragma unroll
    for (int i = 0; i < 16; ++i) {
        int n = (threadIdx.x >> 6) + i * 4;
        WT[(size_t)(n0 + n) * 3072 + k0 + kk] = f2bf(tile[kk][n]);
    }
}

// ---------- CSR build over (dst*8 + rel) bins ----------
__global__ __launch_bounds__(256) void k_hist2(const int* __restrict__ dst,
                                               const int* __restrict__ rel,
                                               int* __restrict__ cnt) {
    int e = blockIdx.x * 256 + threadIdx.x;
    atomicAdd(&cnt[dst[e] * 8 + rel[e]], 1);
}

__global__ __launch_bounds__(1024) void k_scan2(const int* __restrict__ cnt,
                                                int* __restrict__ rowptr,
                                                int* __restrict__ cursor) {
    __shared__ int part[1024];
    const int t = threadIdx.x;
    const int base = t * 128;
    int s = 0;
    for (int i = 0; i < 128; ++i) s += cnt[base + i];
    part[t] = s;
    __syncthreads();
    for (int off = 1; off < 1024; off <<= 1) {
        int v = (t >= off) ? part[t - off] : 0;
        __syncthreads();
        part[t] += v;
        __syncthreads();
    }
    int run = (t == 0) ? 0 : part[t - 1];
    for (int i = 0; i < 128; ++i) {
        int c = cnt[base + i];
        rowptr[base + i] = run;
        cursor[base + i] = run;
        run += c;
    }
    if (t == 1023) rowptr[NBINS] = run;
}

__global__ __launch_bounds__(256) void k_scatter2(const int* __restrict__ src,
                                                  const int* __restrict__ dst,
                                                  const int* __restrict__ rel,
                                                  const float* __restrict__ norm,
                                                  int* __restrict__ cursor,
                                                  int* __restrict__ esrc,
                                                  float* __restrict__ enorm) {
    int e = blockIdx.x * 256 + threadIdx.x;
    int pos = atomicAdd(&cursor[dst[e] * 8 + rel[e]], 1);
    esrc[pos] = src[e];
    enorm[pos] = norm[e];
}

// ---------- agg-first: AGG[d][r*512+f] = sum_{e in bin(d,r)} norm_e * x[src_e][f] ----------
// block per dst, 256 threads x 2 feats (u32 loads); bins of a dst are contiguous in CSR
__global__ __launch_bounds__(256) void k_agg2(const u16* __restrict__ x,
                                              const int* __restrict__ rowptr,
                                              const int* __restrict__ esrc,
                                              const float* __restrict__ enorm,
                                              u16* __restrict__ AGG) {
    const int d = blockIdx.x, t = threadIdx.x;
    const u32* xw = (const u32*)x;
    u32* aggw = (u32*)AGG;
#pragma unroll
    for (int r = 0; r < NRELS; ++r) {
        const int beg = rowptr[d * 8 + r], end = rowptr[d * 8 + r + 1];
        float a0 = 0.f, a1 = 0.f;
        int p = beg;
        for (; p + 2 <= end; p += 2) {
            int   s0 = esrc[p],   s1 = esrc[p + 1];
            float n0 = enorm[p],  n1 = enorm[p + 1];
            u32 w0 = xw[((size_t)s0 << 8) + t];
            u32 w1 = xw[((size_t)s1 << 8) + t];
            a0 = fmaf(n0, bf2f((u16)w0), a0); a1 = fmaf(n0, bf2f((u16)(w0 >> 16)), a1);
            a0 = fmaf(n1, bf2f((u16)w1), a0); a1 = fmaf(n1, bf2f((u16)(w1 >> 16)), a1);
        }
        if (p < end) {
            int s0 = esrc[p];
            float n0 = enorm[p];
            u32 w0 = xw[((size_t)s0 << 8) + t];
            a0 = fmaf(n0, bf2f((u16)w0), a0); a1 = fmaf(n0, bf2f((u16)(w0 >> 16)), a1);
        }
        u32 o = (u32)f2bf(a0) | ((u32)f2bf(a1) << 16);
        aggw[(size_t)d * 2048 + r * 256 + t] = o;
    }
}

// ---------- layer GEMM: xb[16384,512] = relu(AGG[16384,4096] @ WstackT^T + b_gcn) ----------
// tile 128x128, BK=64, 256 threads, 2-phase dbuf, both-sides XOR swizzle, XCD swizzle
__global__ __launch_bounds__(256, 2) void k_gemm(const u16* __restrict__ A,
                                                 const u16* __restrict__ BT,
                                                 u16* __restrict__ C,
                                                 const float* __restrict__ bias) {
    __shared__ __align__(16) u16 As[2][128 * 64];
    __shared__ __align__(16) u16 Bs[2][128 * 64];

    const int t = threadIdx.x;
    const int K = KAGG;
    // grid (128 M-tiles, 4 N-tiles) -> nwg=512; XCD chunk swizzle (%8==0)
    const int lin = blockIdx.y * 128 + blockIdx.x;
    const int swz = (lin & 7) * 64 + (lin >> 3);
    const int tileM = (swz >> 2) * 128;
    const int tileN = (swz & 3) * 128;

    const int w = t >> 6, l = t & 63;
    const int wr = w >> 1, wc = w & 1;
    const int lo = l & 15, hi = l >> 4;

    const int srow8 = l >> 3;
    const int scol = ((l & 7) ^ srow8) * 8;   // pre-swizzled source chunk

    f32x4 acc[4][4];
#pragma unroll
    for (int m = 0; m < 4; ++m)
#pragma unroll
        for (int n = 0; n < 4; ++n) acc[m][n] = f32x4{0.f, 0.f, 0.f, 0.f};

    const int nt = K >> 6;   // 64 k-steps

    // prologue: stage tile 0 into buf 0
#pragma unroll
    for (int i = 0; i < 4; ++i) {
        const int rowblk = (w * 4 + i) * 8;
        gload16(A + (size_t)(tileM + rowblk + srow8) * K + scol, &As[0][rowblk * 64]);
        gload16(BT + (size_t)(tileN + rowblk + srow8) * K + scol, &Bs[0][rowblk * 64]);
    }

    int cur = 0;
    for (int tt = 0; tt < nt; ++tt) {
        __syncthreads();   // drains staging of buf[cur]; protects buf[cur^1] re-staging

        if (tt + 1 < nt) {
            const int k0 = (tt + 1) << 6;
#pragma unroll
            for (int i = 0; i < 4; ++i) {
                const int rowblk = (w * 4 + i) * 8;
                gload16(A + (size_t)(tileM + rowblk + srow8) * K + k0 + scol,
                        &As[cur ^ 1][rowblk * 64]);
                gload16(BT + (size_t)(tileN + rowblk + srow8) * K + k0 + scol,
                        &Bs[cur ^ 1][rowblk * 64]);
            }
        }

        const char* Ab = (const char*)&As[cur][0];
        const char* Bb = (const char*)&Bs[cur][0];
#pragma unroll
        for (int kk = 0; kk < 2; ++kk) {
            s16x8 af[4], bf[4];
#pragma unroll
            for (int m = 0; m < 4; ++m) {
                int row = wr * 64 + m * 16 + lo;
                int boff = (row * 128 + kk * 64 + hi * 16) ^ ((row & 7) << 4);
                af[m] = *(const s16x8*)(Ab + boff);
            }
#pragma unroll
            for (int n = 0; n < 4; ++n) {
                int row = wc * 64 + n * 16 + lo;
                int boff = (row * 128 + kk * 64 + hi * 16) ^ ((row & 7) << 4);
                bf[n] = *(const s16x8*)(Bb + boff);
            }
#pragma unroll
            for (int m = 0; m < 4; ++m)
#pragma unroll
                for (int n = 0; n < 4; ++n)
                    acc[m][n] = __builtin_amdgcn_mfma_f32_16x16x32_bf16(
                        af[m], bf[n], acc[m][n], 0, 0, 0);
        }
        cur ^= 1;
    }

    // epilogue: bias + relu; C/D layout col=lane&15, row=(lane>>4)*4+reg
#pragma unroll
    for (int m = 0; m < 4; ++m)
#pragma unroll
        for (int n = 0; n < 4; ++n) {
            int col = tileN + wc * 64 + n * 16 + lo;
            float bv = bias[col];
#pragma unroll
            for (int j = 0; j < 4; ++j) {
                int row = tileM + wr * 64 + m * 16 + hi * 4 + j;
                C[(size_t)row * HID + col] = f2bf(fmaxf(acc[m][n][j] + bv, 0.f));
            }
        }
}

// ---------- ELMo GEMM: split-K, reg-staged f32 A (double reg buf) + dbuf LDS, pipelined ----------
// grid dim3(2, 128, KSPLIT); writes f32 partials Cp[kz][16384][256]
__global__ __launch_bounds__(256) void k_gemm_elmo(const float* __restrict__ A,
                                                   const u16* __restrict__ BT,
                                                   float* __restrict__ Cp) {
    __shared__ __align__(16) u16 As0[128 * 64], As1[128 * 64];
    __shared__ __align__(16) u16 Bs0[128 * 64], Bs1[128 * 64];

    const int t = threadIdx.x;
    const int tileN = blockIdx.x * 128;
    const int tileM = blockIdx.y * 128;
    const int kz = blockIdx.z;

    const int w = t >> 6, l = t & 63;
    const int wr = w >> 1, wc = w & 1;
    const int lo = l & 15, hi = l >> 4;

    const int srow8 = l >> 3;
    const int scol = ((l & 7) ^ srow8) * 8;   // swizzled global chunk
    const int ldsoff = (l & 7) * 8;           // linear LDS chunk (read applies XOR)

    f32x4 acc[4][4];
#pragma unroll
    for (int m = 0; m < 4; ++m)
#pragma unroll
        for (int n = 0; n < 4; ++n) acc[m][n] = f32x4{0.f, 0.f, 0.f, 0.f};

    const int kbeg = kz * (INDIM / KSPLIT);   // 768 per split, 12 k-steps

    f32x4 a0[8], a1[8];

#define LOADA(dstreg, kofs)                                                           \
    {                                                                                 \
        _Pragma("unroll") for (int i = 0; i < 4; ++i) {                               \
            const float* ap =                                                         \
                A + (size_t)(tileM + (w * 4 + i) * 8 + srow8) * INDIM + (kofs) + scol;\
            dstreg[i * 2] = *(const f32x4*)ap;                                        \
            dstreg[i * 2 + 1] = *(const f32x4*)(ap + 4);                              \
        }                                                                             \
    }
#define WRITEA(srcreg, lds)                                                           \
    {                                                                                 \
        _Pragma("unroll") for (int i = 0; i < 4; ++i) {                               \
            u16x8 wv;                                                                 \
            _Pragma("unroll") for (int j = 0; j < 4; ++j) {                           \
                wv[j] = f2bf(srcreg[i * 2][j]);                                       \
                wv[j + 4] = f2bf(srcreg[i * 2 + 1][j]);                               \
            }                                                                         \
            *(u16x8*)&lds[((w * 4 + i) * 8 + srow8) * 64 + ldsoff] = wv;              \
        }                                                                             \
    }
#define LOADB(lds, kofs)                                                              \
    {                                                                                 \
        _Pragma("unroll") for (int i = 0; i < 4; ++i) {                               \
            const int rowblk = (w * 4 + i) * 8;                                       \
            gload16(BT + (size_t)(tileN + rowblk + srow8) * INDIM + (kofs) + scol,    \
                    &lds[rowblk * 64]);                                               \
        }                                                                             \
    }
#define DOMFMA(Alds, Blds)                                                            \
    {                                                                                 \
        const char* Ab = (const char*)&Alds[0];                                       \
        const char* Bb = (const char*)&Blds[0];                                       \
        _Pragma("unroll") for (int kk = 0; kk < 2; ++kk) {                            \
            s16x8 af[4], bf[4];                                                       \
            _Pragma("unroll") for (int m = 0; m < 4; ++m) {                           \
                int row = wr * 64 + m * 16 + lo;                                      \
                int boff = (row * 128 + kk * 64 + hi * 16) ^ ((row & 7) << 4);        \
                af[m] = *(const s16x8*)(Ab + boff);                                   \
            }                                                                         \
            _Pragma("unroll") for (int n = 0; n < 4; ++n) {                           \
                int row = wc * 64 + n * 16 + lo;                                      \
                int boff = (row * 128 + kk * 64 + hi * 16) ^ ((row & 7) << 4);        \
                bf[n] = *(const s16x8*)(Bb + boff);                                   \
            }                                                                         \
            _Pragma("unroll") for (int m = 0; m < 4; ++m)                             \
                _Pragma("unroll") for (int n = 0; n < 4; ++n)                         \
                    acc[m][n] = __builtin_amdgcn_mfma_f32_16x16x32_bf16(              \
                        af[m], bf[n], acc[m][n], 0, 0, 0);                            \
        }                                                                             \
    }

    // prologue
    LOADA(a0, kbeg);
    LOADB(Bs0, kbeg);

    const int NT2 = (INDIM / KSPLIT) / 128;   // 6 double-steps
    for (int t2 = 0; t2 < NT2; ++t2) {
        const int ke = kbeg + t2 * 128;
        WRITEA(a0, As0);
        __syncthreads();
        LOADA(a1, ke + 64);
        LOADB(Bs1, ke + 64);
        DOMFMA(As0, Bs0);
        WRITEA(a1, As1);
        __syncthreads();
        if (t2 + 1 < NT2) {
            LOADA(a0, ke + 128);
            LOADB(Bs0, ke + 128);
        }
        DOMFMA(As1, Bs1);
    }
#undef LOADA
#undef WRITEA
#undef LOADB
#undef DOMFMA

    float* cp = Cp + (size_t)kz * TOT * 256;
#pragma unroll
    for (int m = 0; m < 4; ++m)
#pragma unroll
        for (int n = 0; n < 4; ++n) {
            int col = tileN + wc * 64 + n * 16 + lo;
#pragma unroll
            for (int j = 0; j < 4; ++j) {
                int row = tileM + wr * 64 + m * 16 + hi * 4 + j;
                cp[(size_t)row * 256 + col] = acc[m][n][j];
            }
        }
}

// ---------- ELMo reduce: xb[:, 0:256] = relu(sum_kz Cp + bias) ----------
__global__ __launch_bounds__(256) void k_elmo_reduce(const float* __restrict__ Cp,
                                                     const float* __restrict__ bias,
                                                     u16* __restrict__ xb) {
    int idx = blockIdx.x * 256 + threadIdx.x;   // 16384*256/4 = 1,048,576
    int row = idx >> 6;
    int c4 = (idx & 63) * 4;
    f32x4 s = *(const f32x4*)(Cp + (size_t)row * 256 + c4);
#pragma unroll
    for (int p = 1; p < KSPLIT; ++p)
        s += *(const f32x4*)(Cp + (size_t)p * TOT * 256 + (size_t)row * 256 + c4);
    f32x4 bv = *(const f32x4*)(bias + c4);
    u16x4 o;
#pragma unroll
    for (int j = 0; j < 4; ++j) o[j] = f2bf(fmaxf(s[j] + bv[j], 0.f));
    *(u16x4*)(xb + (size_t)row * HID + c4) = o;
}

// ---------- final stage 1: per-(graph, 64-node chunk) feature sums ----------
__global__ __launch_bounds__(512) void k_mean1(const u16* __restrict__ xb,
                                               float* __restrict__ part) {
    int g = blockIdx.x >> 4, chunk = blockIdx.x & 15, t = threadIdx.x;
    const u16* base = xb + ((size_t)g * NODESPER + chunk * 64) * HID;
    float s = 0.f;
    for (int n = 0; n < 64; ++n) s += bf2f(base[(size_t)n * HID + t]);
    part[(size_t)blockIdx.x * HID + t] = s;
}

// ---------- final stage 2: reduce partials -> mean -> logits -> softmax ----------
__global__ __launch_bounds__(512) void k_final2(const float* __restrict__ part,
                                                const float* __restrict__ W_out,
                                                const float* __restrict__ b_out,
                                                float* __restrict__ out) {
    int g = blockIdx.x, t = threadIdx.x;
    __shared__ float mean_s[512];
    __shared__ float lg[128];
    __shared__ float red[128];
    float s = 0.f;
#pragma unroll
    for (int c = 0; c < 16; ++c) s += part[((size_t)g * 16 + c) * HID + t];
    mean_s[t] = s * (1.0f / (float)NODESPER);
    __syncthreads();
    if (t < NOUT) {
        float a = b_out[t];
        for (int k = 0; k < HID; ++k) a = fmaf(mean_s[k], W_out[(size_t)k * NOUT + t], a);
        lg[t] = a;
        red[t] = a;
    }
    __syncthreads();
    for (int off = 64; off > 0; off >>= 1) {
        if (t < off) red[t] = fmaxf(red[t], red[t + off]);
        __syncthreads();
    }
    float mx = red[0];
    __syncthreads();
    if (t < NOUT) { float e = expf(lg[t] - mx); lg[t] = e; red[t] = e; }
    __syncthreads();
    for (int off = 64; off > 0; off >>= 1) {
        if (t < off) red[t] += red[t + off];
        __syncthreads();
    }
    if (t < NOUT) out[(size_t)g * NOUT + t] = lg[t] / red[0];
}

extern "C" void kernel_launch(void* const* d_in, const int* in_sizes, int n_in,
                              void* d_out, int out_size, void* d_ws, size_t ws_size,
                              hipStream_t stream) {
    const float* h      = (const float*)d_in[0];
    const int*   src    = (const int*)d_in[1];
    const int*   dst    = (const int*)d_in[2];
    const int*   rel    = (const int*)d_in[3];
    const float* norm   = (const float*)d_in[4];
    const float* W_elmo = (const float*)d_in[5];
    const float* b_elmo = (const float*)d_in[6];
    const float* comp   = (const float*)d_in[7];
    const float* V      = (const float*)d_in[8];
    const float* b_gcn  = (const float*)d_in[9];
    const float* W_out  = (const float*)d_in[10];
    const float* b_out  = (const float*)d_in[11];
    float* out = (float*)d_out;

    char* ws = (char*)d_ws;
    u16*   xb      = (u16*)(ws + OFF_XB);
    u16*   agg     = (u16*)(ws + OFF_AGG);
    float* elmoP   = (float*)(ws + OFF_AGG);   // dead once elmo_reduce completes
    u16*   wstackT = (u16*)(ws + OFF_WST);
    u16*   welmoT  = (u16*)(ws + OFF_WET);
    int*   cnt2    = (int*)(ws + OFF_CNT2);
    int*   rowptr2 = (int*)(ws + OFF_ROWPTR2);
    int*   cursor2 = (int*)(ws + OFF_CURSOR2);
    int*   esrc    = (int*)(ws + OFF_ESRC);
    float* enorm   = (float*)(ws + OFF_ENORM);
    float* part    = (float*)(ws + OFF_PART);

    // zero x buffer (upper 256 feature dims stay 0 for layer-1 input) and histogram
    hipMemsetAsync(xb, 0, (size_t)TOT * HID * 2, stream);
    hipMemsetAsync(cnt2, 0, (size_t)NBINS * 4, stream);

    k_prep_wstack<<<dim3(8, 8, 8), 256, 0, stream>>>(comp, V, wstackT);
    k_prep_welmo<<<dim3(48, 4), 256, 0, stream>>>(W_elmo, welmoT);

    k_hist2<<<EDGES / 256, 256, 0, stream>>>(dst, rel, cnt2);
    k_scan2<<<1, 1024, 0, stream>>>(cnt2, rowptr2, cursor2);
    k_scatter2<<<EDGES / 256, 256, 0, stream>>>(src, dst, rel, norm, cursor2, esrc, enorm);

    // ELMo: xb[:, 0:256] = relu(h @ W_elmo + b_elmo)  (M=16384, K=3072 split x4, N=256)
    k_gemm_elmo<<<dim3(2, 128, KSPLIT), 256, 0, stream>>>(h, welmoT, elmoP);
    k_elmo_reduce<<<4096, 256, 0, stream>>>(elmoP, b_elmo, xb);

    for (int L = 0; L < 3; ++L) {
        // AGG[d][r*512+f] = sum_{e in bin(d,r)} norm_e * xb[src_e][f]
        k_agg2<<<TOT, 256, 0, stream>>>(xb, rowptr2, esrc, enorm, agg);
        // xb = relu(AGG @ Wstack + b_gcn)   (M=16384, K=4096, N=512)
        k_gemm<<<dim3(128, 4), 256, 0, stream>>>(agg, wstackT, xb, b_gcn);
    }

    k_mean1<<<NGRAPH * 16, 512, 0, stream>>>(xb, part);
    k_final2<<<NGRAPH, 512, 0, stream>>>(part, W_out, b_out, out);
}

// Round 6
// 580.412 us; speedup vs baseline: 1.0946x; 1.0946x over previous
//
#include <hip/hip_runtime.h>

typedef unsigned short u16;
typedef unsigned int   u32;
typedef u16   u16x4 __attribute__((ext_vector_type(4)));
typedef u16   u16x8 __attribute__((ext_vector_type(8)));
typedef short s16x8 __attribute__((ext_vector_type(8)));
typedef u32   u32x4 __attribute__((ext_vector_type(4)));
typedef float f32x4 __attribute__((ext_vector_type(4)));

// ---------- bf16 helpers (bit-level, RNE) ----------
__device__ __forceinline__ float bf2f(u16 u) {
    u32 x = ((u32)u) << 16;
    return __builtin_bit_cast(float, x);
}
__device__ __forceinline__ u16 f2bf(float f) {
    u32 u = __builtin_bit_cast(u32, f);
    u32 r = u + 0x7FFFu + ((u >> 16) & 1u);
    return (u16)(r >> 16);
}
// packed f32x2 -> bf16x2 (RNE), lo = src0
__device__ __forceinline__ u32 cvtpk(float a, float b) {
    u32 r;
    asm("v_cvt_pk_bf16_f32 %0, %1, %2" : "=v"(r) : "v"(a), "v"(b));
    return r;
}

// async global->LDS, 16B per lane; lds dest is wave-uniform base (HW: base + lane*16)
__device__ __forceinline__ void gload16(const void* g, void* lds) {
    __builtin_amdgcn_global_load_lds((const __attribute__((address_space(1))) void*)g,
                                     (__attribute__((address_space(3))) void*)lds, 16, 0, 0);
}

// ---------- sizes ----------
#define TOT   16384      // BS*N nodes
#define HID   512
#define NRELS 8
#define EDGES 262144
#define INDIM 3072
#define NOUT  128
#define NGRAPH 16
#define NODESPER 1024
#define EKSPLIT 2        // ELMo split-K: 1536 per block
#define ENT    48        // ELMo k-steps (1536/32)

// workspace layout (16B aligned)
#define OFF_XB     ((size_t)0)                    // u16 [16384][512]   16,777,216 B
#define OFF_Y      (OFF_XB + 16777216)            // u16 [16384][4096] 134,217,728 B (also ELMo f32 partials [2][16384][256] = 33.5 MB)
#define OFF_WCT    (OFF_Y + 134217728)            // u16 [4096][512]     4,194,304 B
#define OFF_WET    (OFF_WCT + 4194304)            // u16 [256][3072]     1,572,864 B
#define OFF_CNT    (OFF_WET + 1572864)            // int [16384]
#define OFF_ROWPTR (OFF_CNT + 65536)              // int [16385] (+pad)
#define OFF_CURSOR (OFF_ROWPTR + 65552)           // int [16384]
#define OFF_EPK    (OFF_CURSOR + 65536)           // int [262144]
#define OFF_ENORM  (OFF_EPK + 1048576)            // float [262144]
#define OFF_PART   (OFF_ENORM + 1048576)          // float [256][512]

// ---------- prep: WcatT[(r*512+n)][k] = sum_b comp[r,b] * V[b][k][n]  (LDS transpose) ----------
__global__ __launch_bounds__(256) void k_prep_wcat(const float* __restrict__ comp,
                                                   const float* __restrict__ V,
                                                   u16* __restrict__ WcatT) {
    __shared__ float tile[64][65];
    const int r = blockIdx.z, k0 = blockIdx.x * 64, n0 = blockIdx.y * 64;
    const float c0 = comp[r * 4], c1 = comp[r * 4 + 1], c2 = comp[r * 4 + 2], c3 = comp[r * 4 + 3];
    const int tn = threadIdx.x & 63;   // n fast -> coalesced V reads
    const int tk = threadIdx.x >> 6;
#pragma unroll
    for (int i = 0; i < 16; ++i) {
        int k = tk + i * 4;
        const float* vp = V + (size_t)(k0 + k) * 512 + n0 + tn;
        tile[k][tn] = c0 * vp[0] + c1 * vp[262144] + c2 * vp[2 * 262144] + c3 * vp[3 * 262144];
    }
    __syncthreads();
    const int kk = threadIdx.x & 63;   // k fast -> coalesced writes
#pragma unroll
    for (int i = 0; i < 16; ++i) {
        int n = (threadIdx.x >> 6) + i * 4;
        WcatT[((size_t)(r * 512 + n0 + n) << 9) + k0 + kk] = f2bf(tile[kk][n]);
    }
}

// ---------- prep: WelmoT[n][k] = W_elmo[k][n] (LDS transpose) ----------
__global__ __launch_bounds__(256) void k_prep_welmo(const float* __restrict__ W,
                                                    u16* __restrict__ WT) {
    __shared__ float tile[64][65];
    const int k0 = blockIdx.x * 64, n0 = blockIdx.y * 64;
    const int tn = threadIdx.x & 63;
    const int tk = threadIdx.x >> 6;
#pragma unroll
    for (int i = 0; i < 16; ++i) {
        int k = tk + i * 4;
        tile[k][tn] = W[(size_t)(k0 + k) * 256 + n0 + tn];
    }
    __syncthreads();
    const int kk = threadIdx.x & 63;
#pragma unroll
    for (int i = 0; i < 16; ++i) {
        int n = (threadIdx.x >> 6) + i * 4;
        WT[(size_t)(n0 + n) * 3072 + k0 + kk] = f2bf(tile[kk][n]);
    }
}

// ---------- CSR build (dst-keyed) ----------
__global__ __launch_bounds__(256) void k_hist(const int* __restrict__ dst, int* __restrict__ cnt) {
    int e = blockIdx.x * 256 + threadIdx.x;
    atomicAdd(&cnt[dst[e]], 1);
}

__global__ __launch_bounds__(1024) void k_scan(const int* __restrict__ cnt,
                                               int* __restrict__ rowptr,
                                               int* __restrict__ cursor) {
    __shared__ int part[1024];
    int t = threadIdx.x;
    int loc[16];
    int s = 0;
    int base = t * 16;
#pragma unroll
    for (int i = 0; i < 16; ++i) { loc[i] = s; s += cnt[base + i]; }
    part[t] = s;
    __syncthreads();
    for (int off = 1; off < 1024; off <<= 1) {
        int v = (t >= off) ? part[t - off] : 0;
        __syncthreads();
        part[t] += v;
        __syncthreads();
    }
    int excl = (t == 0) ? 0 : part[t - 1];
#pragma unroll
    for (int i = 0; i < 16; ++i) {
        int v = excl + loc[i];
        rowptr[base + i] = v;
        cursor[base + i] = v;
    }
    if (t == 1023) rowptr[TOT] = part[1023];
}

__global__ __launch_bounds__(256) void k_scatter(const int* __restrict__ src,
                                                 const int* __restrict__ dst,
                                                 const int* __restrict__ rel,
                                                 const float* __restrict__ norm,
                                                 int* __restrict__ cursor,
                                                 int* __restrict__ epk,
                                                 float* __restrict__ enorm) {
    int e = blockIdx.x * 256 + threadIdx.x;
    int d = dst[e];
    int pos = atomicAdd(&cursor[d], 1);
    epk[pos] = (src[e] << 3) | rel[e];
    enorm[pos] = norm[e];
}

// ---------- layer GEMM (m97 structure, single-buffer, 4 blocks/CU): C = A @ BT^T ----------
// tile 128x128, BK=64, 256 threads; global_load_lds width-16, both-sides XOR swizzle
__global__ __launch_bounds__(256, 4) void k_gemm(const u16* __restrict__ A,
                                                 const u16* __restrict__ BT,
                                                 u16* __restrict__ C,
                                                 int K, int lda, int ldb, int ldc) {
    __shared__ __align__(16) u16 As[128 * 64];
    __shared__ __align__(16) u16 Bs[128 * 64];

    const int t = threadIdx.x;
    // XCD-aware bijective chunk swizzle (nwg = 128*32 = 4096, %8 == 0)
    const int lin = blockIdx.y * 128 + blockIdx.x;
    const int swz = (lin & 7) * 512 + (lin >> 3);
    const int tileM = (swz & 127) * 128;
    const int tileN = (swz >> 7) * 128;

    const int w = t >> 6, l = t & 63;
    const int wr = w >> 1, wc = w & 1;
    const int lo = l & 15, hi = l >> 4;

    const int srow8 = l >> 3;
    const int scol = ((l & 7) ^ srow8) * 8;   // pre-swizzled source 16B-chunk (u16 units)

    f32x4 acc[4][4];
#pragma unroll
    for (int m = 0; m < 4; ++m)
#pragma unroll
        for (int n = 0; n < 4; ++n) acc[m][n] = f32x4{0.f, 0.f, 0.f, 0.f};

    for (int k0 = 0; k0 < K; k0 += 64) {
#pragma unroll
        for (int i = 0; i < 4; ++i) {
            const int rowblk = (w * 4 + i) * 8;            // wave-uniform
            gload16(A + (size_t)(tileM + rowblk + srow8) * lda + k0 + scol, &As[rowblk * 64]);
            gload16(BT + (size_t)(tileN + rowblk + srow8) * ldb + k0 + scol, &Bs[rowblk * 64]);
        }
        __syncthreads();

#pragma unroll
        for (int kk = 0; kk < 2; ++kk) {
            s16x8 af[4], bf[4];
#pragma unroll
            for (int m = 0; m < 4; ++m) {
                int row = wr * 64 + m * 16 + lo;
                int boff = (row * 128 + kk * 64 + hi * 16) ^ ((row & 7) << 4);
                af[m] = *(const s16x8*)((const char*)As + boff);
            }
#pragma unroll
            for (int n = 0; n < 4; ++n) {
                int row = wc * 64 + n * 16 + lo;
                int boff = (row * 128 + kk * 64 + hi * 16) ^ ((row & 7) << 4);
                bf[n] = *(const s16x8*)((const char*)Bs + boff);
            }
#pragma unroll
            for (int m = 0; m < 4; ++m)
#pragma unroll
                for (int n = 0; n < 4; ++n)
                    acc[m][n] = __builtin_amdgcn_mfma_f32_16x16x32_bf16(
                        af[m], bf[n], acc[m][n], 0, 0, 0);
        }
        __syncthreads();
    }

    // epilogue: C/D layout col=lane&15, row=(lane>>4)*4+reg
#pragma unroll
    for (int m = 0; m < 4; ++m)
#pragma unroll
        for (int n = 0; n < 4; ++n) {
            int col = tileN + wc * 64 + n * 16 + lo;
#pragma unroll
            for (int j = 0; j < 4; ++j) {
                int row = tileM + wr * 64 + m * 16 + hi * 4 + j;
                C[(size_t)row * ldc + col] = f2bf(acc[m][n][j]);
            }
        }
}

// ---------- ELMo GEMM: ring-4 counted-vmcnt pipeline, f32 A via global_load_lds ----------
// BM=32, BN=256, BK=32, KSPLIT=2. grid dim3(512, 2), 256 threads (4 waves, 1M x 4N).
// LDS: A 4 slots x [32][32] f32 (16KB), B 4 slots x [128 rows x 128B] (64KB) = 80KB -> 2 blk/CU.
// 3 slots in flight; per step 5 vmem instr -> steady-state wait vmcnt(10).
__global__ __launch_bounds__(256, 2) void k_gemm_elmo(const float* __restrict__ A,
                                                      const u16* __restrict__ BT,
                                                      float* __restrict__ Cp) {
    __shared__ __align__(16) float As[4][1024];   // [slot][32 rows * 32 f32], row = 128B, XOR-swizzled
    __shared__ __align__(16) u16   Bs[4][8192];   // [slot][128 LDS-rows * 128B]; 2 B-rows per LDS-row

    const int t = threadIdx.x;
    const int w = t >> 6, l = t & 63;
    const int lo = l & 15, hi = l >> 4;
    const int tileM = blockIdx.x * 32;
    const int kbeg = blockIdx.y * (INDIM / EKSPLIT);   // 1536 per split

    // ---- staging addressing (both-sides swizzle, derived per rules #21) ----
    const int x16 = (l & 7) ^ (l >> 3);          // swizzled chunk selector
    const int r7w = w * 8 + (l >> 3);            // lane's LDS row within wave's 8-row group
    // A: lane sources f32 col 4*x16 of row (tileM + r7w); HW writes lds base + l*16
    const float* aSrc = A + (size_t)(tileM + r7w) * INDIM + kbeg + 4 * x16;
    // B: x = 16*x16 -> rb = (x>>6)*128 + c*32 + r7w, colbyte = x&63
    const int rbHalf = (x16 >> 2) * 128;         // (x>>6)*128 with x=16*x16
    const int bcol = ((16 * x16) & 63) >> 1;     // bf16 col: 0/8/16/24

    f32x4 acc[2][4];
#pragma unroll
    for (int m = 0; m < 2; ++m)
#pragma unroll
        for (int n = 0; n < 4; ++n) acc[m][n] = f32x4{0.f, 0.f, 0.f, 0.f};

#define ESTAGE(step)                                                                    \
    {                                                                                   \
        const int slot_ = (step) & 3;                                                   \
        const int kofs_ = (step) * 32;                                                  \
        gload16(aSrc + kofs_, &As[slot_][w * 256]);                                     \
        _Pragma("unroll") for (int c = 0; c < 4; ++c) {                                 \
            gload16(BT + (size_t)(rbHalf + c * 32 + r7w) * INDIM + kbeg + kofs_ + bcol, \
                    &Bs[slot_][c * 2048 + w * 512]);                                    \
        }                                                                               \
    }

    // prologue: stage slots 0,1,2 (15 vmem instructions outstanding)
    ESTAGE(0);
    ESTAGE(1);
    ESTAGE(2);

    for (int st = 0; st < ENT; ++st) {
        __builtin_amdgcn_sched_barrier(0);
        if (st < ENT - 2)       asm volatile("s_waitcnt vmcnt(10)" ::: "memory");
        else if (st == ENT - 2) asm volatile("s_waitcnt vmcnt(5)" ::: "memory");
        else                    asm volatile("s_waitcnt vmcnt(0)" ::: "memory");
        __builtin_amdgcn_s_barrier();
        __builtin_amdgcn_sched_barrier(0);

        if (st + 3 < ENT) ESTAGE(st + 3);

        const char* Ab = (const char*)As[st & 3];
        const char* Bb = (const char*)Bs[st & 3];

        s16x8 afr[2], bfr[4];
#pragma unroll
        for (int m = 0; m < 2; ++m) {
            int ra = m * 16 + lo;
            int sw = (ra & 7) << 4;
            f32x4 p = *(const f32x4*)(Ab + ra * 128 + ((hi * 32) ^ sw));
            f32x4 q = *(const f32x4*)(Ab + ra * 128 + ((hi * 32 + 16) ^ sw));
            u32x4 pk = {cvtpk(p[0], p[1]), cvtpk(p[2], p[3]),
                        cvtpk(q[0], q[1]), cvtpk(q[2], q[3])};
            afr[m] = __builtin_bit_cast(s16x8, pk);
        }
#pragma unroll
        for (int n = 0; n < 4; ++n) {
            int rb = w * 64 + n * 16 + lo;
            int off = (rb & 127) * 128 + ((((rb >> 7) << 6) | (hi << 4)) ^ ((rb & 7) << 4));
            bfr[n] = *(const s16x8*)(Bb + off);
        }
#pragma unroll
        for (int m = 0; m < 2; ++m)
#pragma unroll
            for (int n = 0; n < 4; ++n)
                acc[m][n] = __builtin_amdgcn_mfma_f32_16x16x32_bf16(
                    afr[m], bfr[n], acc[m][n], 0, 0, 0);
        __builtin_amdgcn_sched_barrier(0);
    }
#undef ESTAGE

    float* cp = Cp + (size_t)blockIdx.y * TOT * 256;
#pragma unroll
    for (int m = 0; m < 2; ++m)
#pragma unroll
        for (int n = 0; n < 4; ++n) {
            int col = w * 64 + n * 16 + lo;
#pragma unroll
            for (int j = 0; j < 4; ++j) {
                int row = tileM + m * 16 + hi * 4 + j;
                cp[(size_t)row * 256 + col] = acc[m][n][j];
            }
        }
}

// ---------- ELMo reduce: xb[:, 0:256] = relu(sum_kz Cp + bias) ----------
__global__ __launch_bounds__(256) void k_elmo_reduce(const float* __restrict__ Cp,
                                                     const float* __restrict__ bias,
                                                     u16* __restrict__ xb) {
    int idx = blockIdx.x * 256 + threadIdx.x;   // 16384*256/4 = 1,048,576
    int row = idx >> 6;
    int c4 = (idx & 63) * 4;
    f32x4 s = *(const f32x4*)(Cp + (size_t)row * 256 + c4);
#pragma unroll
    for (int p = 1; p < EKSPLIT; ++p)
        s += *(const f32x4*)(Cp + (size_t)p * TOT * 256 + (size_t)row * 256 + c4);
    f32x4 bv = *(const f32x4*)(bias + c4);
    u16x4 o;
#pragma unroll
    for (int j = 0; j < 4; ++j) o[j] = f2bf(fmaxf(s[j] + bv[j], 0.f));
    *(u16x4*)(xb + (size_t)row * HID + c4) = o;
}

// ---------- aggregation: x_new[d] = relu(b + sum_e norm_e * y[src_e, r_e*512 + :]) ----------
// 256 threads, 2 feats/thread (u32), edge meta in LDS chunks of 64, unroll x16
__global__ __launch_bounds__(256) void k_agg(const u16* __restrict__ y,
                                             const int* __restrict__ rowptr,
                                             const int* __restrict__ epk,
                                             const float* __restrict__ enorm,
                                             const float* __restrict__ bgcn,
                                             u16* __restrict__ xout) {
    __shared__ int   s_epk[64];
    __shared__ float s_nrm[64];
    const int d = blockIdx.x, t = threadIdx.x;
    const u32* yw = (const u32*)y;

    float2 bv = *(const float2*)(bgcn + 2 * t);
    float a0 = bv.x, a1 = bv.y;

    const int beg = rowptr[d], end = rowptr[d + 1];
    for (int base = beg; base < end; base += 64) {
        const int m = min(64, end - base);
        if (t < m) { s_epk[t] = epk[base + t]; s_nrm[t] = enorm[base + t]; }
        __syncthreads();
        int c = 0;
        for (; c + 16 <= m; c += 16) {
            u32 wv[16];
            float nv[16];
#pragma unroll
            for (int q = 0; q < 16; ++q) {
                int k = s_epk[c + q];
                nv[q] = s_nrm[c + q];
                wv[q] = yw[((size_t)(k >> 3) << 11) + ((k & 7) << 8) + t];
            }
#pragma unroll
            for (int q = 0; q < 16; ++q) {
                a0 = fmaf(nv[q], bf2f((u16)wv[q]), a0);
                a1 = fmaf(nv[q], bf2f((u16)(wv[q] >> 16)), a1);
            }
        }
        for (; c + 4 <= m; c += 4) {
            u32 wv[4];
            float nv[4];
#pragma unroll
            for (int q = 0; q < 4; ++q) {
                int k = s_epk[c + q];
                nv[q] = s_nrm[c + q];
                wv[q] = yw[((size_t)(k >> 3) << 11) + ((k & 7) << 8) + t];
            }
#pragma unroll
            for (int q = 0; q < 4; ++q) {
                a0 = fmaf(nv[q], bf2f((u16)wv[q]), a0);
                a1 = fmaf(nv[q], bf2f((u16)(wv[q] >> 16)), a1);
            }
        }
        for (; c < m; ++c) {
            int k0 = s_epk[c];
            float n0 = s_nrm[c];
            u32 w0 = yw[((size_t)(k0 >> 3) << 11) + ((k0 & 7) << 8) + t];
            a0 = fmaf(n0, bf2f((u16)w0), a0);
            a1 = fmaf(n0, bf2f((u16)(w0 >> 16)), a1);
        }
        __syncthreads();
    }
    u32 o = (u32)f2bf(fmaxf(a0, 0.f)) | ((u32)f2bf(fmaxf(a1, 0.f)) << 16);
    ((u32*)xout)[((size_t)d << 8) + t] = o;
}

// ---------- final stage 1: per-(graph, 64-node chunk) feature sums ----------
__global__ __launch_bounds__(512) void k_mean1(const u16* __restrict__ xb,
                                               float* __restrict__ part) {
    int g = blockIdx.x >> 4, chunk = blockIdx.x & 15, t = threadIdx.x;
    const u16* base = xb + ((size_t)g * NODESPER + chunk * 64) * HID;
    float s = 0.f;
    for (int n = 0; n < 64; ++n) s += bf2f(base[(size_t)n * HID + t]);
    part[(size_t)blockIdx.x * HID + t] = s;
}

// ---------- final stage 2: reduce partials -> mean -> logits -> softmax ----------
__global__ __launch_bounds__(512) void k_final2(const float* __restrict__ part,
                                                const float* __restrict__ W_out,
                                                const float* __restrict__ b_out,
                                                float* __restrict__ out) {
    int g = blockIdx.x, t = threadIdx.x;
    __shared__ float mean_s[512];
    __shared__ float lg[128];
    __shared__ float red[128];
    float s = 0.f;
#pragma unroll
    for (int c = 0; c < 16; ++c) s += part[((size_t)g * 16 + c) * HID + t];
    mean_s[t] = s * (1.0f / (float)NODESPER);
    __syncthreads();
    if (t < NOUT) {
        float a = b_out[t];
        for (int k = 0; k < HID; ++k) a = fmaf(mean_s[k], W_out[(size_t)k * NOUT + t], a);
        lg[t] = a;
        red[t] = a;
    }
    __syncthreads();
    for (int off = 64; off > 0; off >>= 1) {
        if (t < off) red[t] = fmaxf(red[t], red[t + off]);
        __syncthreads();
    }
    float mx = red[0];
    __syncthreads();
    if (t < NOUT) { float e = expf(lg[t] - mx); lg[t] = e; red[t] = e; }
    __syncthreads();
    for (int off = 64; off > 0; off >>= 1) {
        if (t < off) red[t] += red[t + off];
        __syncthreads();
    }
    if (t < NOUT) out[(size_t)g * NOUT + t] = lg[t] / red[0];
}

extern "C" void kernel_launch(void* const* d_in, const int* in_sizes, int n_in,
                              void* d_out, int out_size, void* d_ws, size_t ws_size,
                              hipStream_t stream) {
    const float* h      = (const float*)d_in[0];
    const int*   src    = (const int*)d_in[1];
    const int*   dst    = (const int*)d_in[2];
    const int*   rel    = (const int*)d_in[3];
    const float* norm   = (const float*)d_in[4];
    const float* W_elmo = (const float*)d_in[5];
    const float* b_elmo = (const float*)d_in[6];
    const float* comp   = (const float*)d_in[7];
    const float* V      = (const float*)d_in[8];
    const float* b_gcn  = (const float*)d_in[9];
    const float* W_out  = (const float*)d_in[10];
    const float* b_out  = (const float*)d_in[11];
    float* out = (float*)d_out;

    char* ws = (char*)d_ws;
    u16*   xb     = (u16*)(ws + OFF_XB);
    u16*   y      = (u16*)(ws + OFF_Y);
    float* elmoP  = (float*)(ws + OFF_Y);  // dead once elmo_reduce completes
    u16*   wcatT  = (u16*)(ws + OFF_WCT);
    u16*   welmoT = (u16*)(ws + OFF_WET);
    int*   cnt    = (int*)(ws + OFF_CNT);
    int*   rowptr = (int*)(ws + OFF_ROWPTR);
    int*   cursor = (int*)(ws + OFF_CURSOR);
    int*   epk    = (int*)(ws + OFF_EPK);
    float* enorm  = (float*)(ws + OFF_ENORM);
    float* part   = (float*)(ws + OFF_PART);

    // zero x buffer (upper 256 feature dims stay 0 for layer-1 input) and histogram
    hipMemsetAsync(xb, 0, (size_t)TOT * HID * 2, stream);
    hipMemsetAsync(cnt, 0, (size_t)TOT * 4, stream);

    k_prep_wcat<<<dim3(8, 8, 8), 256, 0, stream>>>(comp, V, wcatT);
    k_prep_welmo<<<dim3(48, 4), 256, 0, stream>>>(W_elmo, welmoT);

    k_hist<<<EDGES / 256, 256, 0, stream>>>(dst, cnt);
    k_scan<<<1, 1024, 0, stream>>>(cnt, rowptr, cursor);
    k_scatter<<<EDGES / 256, 256, 0, stream>>>(src, dst, rel, norm, cursor, epk, enorm);

    // ELMo: xb[:, 0:256] = relu(h @ W_elmo + b_elmo)  (M=16384, K=3072 split x2, N=256)
    k_gemm_elmo<<<dim3(512, EKSPLIT), 256, 0, stream>>>(h, welmoT, elmoP);
    k_elmo_reduce<<<4096, 256, 0, stream>>>(elmoP, b_elmo, xb);

    for (int L = 0; L < 3; ++L) {
        // y = xb @ Wcat   (M=16384, N=4096; K=256 for layer 1 — xb cols 256.. are zero)
        const int Keff = (L == 0) ? 256 : 512;
        k_gemm<<<dim3(128, 32), 256, 0, stream>>>(xb, wcatT, y, Keff, HID, HID,
                                                  NRELS * HID);
        // xb = relu(b_gcn + segment_sum(norm * y[src, r]))
        k_agg<<<TOT, 256, 0, stream>>>(y, rowptr, epk, enorm, b_gcn, xb);
    }

    k_mean1<<<NGRAPH * 16, 512, 0, stream>>>(xb, part);
    k_final2<<<NGRAPH, 512, 0, stream>>>(part, W_out, b_out, out);
}

// Round 7
// 534.126 us; speedup vs baseline: 1.1895x; 1.0867x over previous
//
#include <hip/hip_runtime.h>

typedef unsigned short u16;
typedef unsigned int   u32;
typedef u16   u16x4 __attribute__((ext_vector_type(4)));
typedef u16   u16x8 __attribute__((ext_vector_type(8)));
typedef short s16x8 __attribute__((ext_vector_type(8)));
typedef u32   u32x4 __attribute__((ext_vector_type(4)));
typedef float f32x4 __attribute__((ext_vector_type(4)));

// ---------- bf16 helpers (bit-level, RNE) ----------
__device__ __forceinline__ float bf2f(u16 u) {
    u32 x = ((u32)u) << 16;
    return __builtin_bit_cast(float, x);
}
__device__ __forceinline__ u16 f2bf(float f) {
    u32 u = __builtin_bit_cast(u32, f);
    u32 r = u + 0x7FFFu + ((u >> 16) & 1u);
    return (u16)(r >> 16);
}
// packed f32x2 -> bf16x2 (RNE), lo = src0
__device__ __forceinline__ u32 cvtpk(float a, float b) {
    u32 r;
    asm("v_cvt_pk_bf16_f32 %0, %1, %2" : "=v"(r) : "v"(a), "v"(b));
    return r;
}

// async global->LDS, 16B per lane; lds dest is wave-uniform base (HW: base + lane*16)
__device__ __forceinline__ void gload16(const void* g, void* lds) {
    __builtin_amdgcn_global_load_lds((const __attribute__((address_space(1))) void*)g,
                                     (__attribute__((address_space(3))) void*)lds, 16, 0, 0);
}

// ---------- sizes ----------
#define TOT   16384      // BS*N nodes
#define HID   512
#define NRELS 8
#define EDGES 262144
#define INDIM 3072
#define NOUT  128
#define NGRAPH 16
#define NODESPER 1024
#define EKSPLIT 4        // ELMo split-K: 768 per block, 12 k-steps

// workspace layout (16B aligned)
#define OFF_XB     ((size_t)0)                    // u16 [16384][512]   16,777,216 B
#define OFF_Y      (OFF_XB + 16777216)            // u16 [16384][4096] 134,217,728 B (also ELMo f32 partials [4][16384][256] = 67 MB)
#define OFF_WCT    (OFF_Y + 134217728)            // u16 [4096][512]     4,194,304 B
#define OFF_WET    (OFF_WCT + 4194304)            // u16 [256][3072]     1,572,864 B
#define OFF_CNT    (OFF_WET + 1572864)            // int [16384]
#define OFF_ROWPTR (OFF_CNT + 65536)              // int [16385] (+pad)
#define OFF_CURSOR (OFF_ROWPTR + 65552)           // int [16384]
#define OFF_EPK    (OFF_CURSOR + 65536)           // int [262144]
#define OFF_ENORM  (OFF_EPK + 1048576)            // float [262144]
#define OFF_PART   (OFF_ENORM + 1048576)          // float [256][512]

// ---------- prep: WcatT[(r*512+n)][k] = sum_b comp[r,b] * V[b][k][n]  (LDS transpose) ----------
__global__ __launch_bounds__(256) void k_prep_wcat(const float* __restrict__ comp,
                                                   const float* __restrict__ V,
                                                   u16* __restrict__ WcatT) {
    __shared__ float tile[64][65];
    const int r = blockIdx.z, k0 = blockIdx.x * 64, n0 = blockIdx.y * 64;
    const float c0 = comp[r * 4], c1 = comp[r * 4 + 1], c2 = comp[r * 4 + 2], c3 = comp[r * 4 + 3];
    const int tn = threadIdx.x & 63;   // n fast -> coalesced V reads
    const int tk = threadIdx.x >> 6;
#pragma unroll
    for (int i = 0; i < 16; ++i) {
        int k = tk + i * 4;
        const float* vp = V + (size_t)(k0 + k) * 512 + n0 + tn;
        tile[k][tn] = c0 * vp[0] + c1 * vp[262144] + c2 * vp[2 * 262144] + c3 * vp[3 * 262144];
    }
    __syncthreads();
    const int kk = threadIdx.x & 63;   // k fast -> coalesced writes
#pragma unroll
    for (int i = 0; i < 16; ++i) {
        int n = (threadIdx.x >> 6) + i * 4;
        WcatT[((size_t)(r * 512 + n0 + n) << 9) + k0 + kk] = f2bf(tile[kk][n]);
    }
}

// ---------- prep: WelmoT[n][k] = W_elmo[k][n] (LDS transpose) ----------
__global__ __launch_bounds__(256) void k_prep_welmo(const float* __restrict__ W,
                                                    u16* __restrict__ WT) {
    __shared__ float tile[64][65];
    const int k0 = blockIdx.x * 64, n0 = blockIdx.y * 64;
    const int tn = threadIdx.x & 63;
    const int tk = threadIdx.x >> 6;
#pragma unroll
    for (int i = 0; i < 16; ++i) {
        int k = tk + i * 4;
        tile[k][tn] = W[(size_t)(k0 + k) * 256 + n0 + tn];
    }
    __syncthreads();
    const int kk = threadIdx.x & 63;
#pragma unroll
    for (int i = 0; i < 16; ++i) {
        int n = (threadIdx.x >> 6) + i * 4;
        WT[(size_t)(n0 + n) * 3072 + k0 + kk] = f2bf(tile[kk][n]);
    }
}

// ---------- CSR build (dst-keyed) ----------
__global__ __launch_bounds__(256) void k_hist(const int* __restrict__ dst, int* __restrict__ cnt) {
    int e = blockIdx.x * 256 + threadIdx.x;
    atomicAdd(&cnt[dst[e]], 1);
}

__global__ __launch_bounds__(1024) void k_scan(const int* __restrict__ cnt,
                                               int* __restrict__ rowptr,
                                               int* __restrict__ cursor) {
    __shared__ int part[1024];
    int t = threadIdx.x;
    int loc[16];
    int s = 0;
    int base = t * 16;
#pragma unroll
    for (int i = 0; i < 16; ++i) { loc[i] = s; s += cnt[base + i]; }
    part[t] = s;
    __syncthreads();
    for (int off = 1; off < 1024; off <<= 1) {
        int v = (t >= off) ? part[t - off] : 0;
        __syncthreads();
        part[t] += v;
        __syncthreads();
    }
    int excl = (t == 0) ? 0 : part[t - 1];
#pragma unroll
    for (int i = 0; i < 16; ++i) {
        int v = excl + loc[i];
        rowptr[base + i] = v;
        cursor[base + i] = v;
    }
    if (t == 1023) rowptr[TOT] = part[1023];
}

__global__ __launch_bounds__(256) void k_scatter(const int* __restrict__ src,
                                                 const int* __restrict__ dst,
                                                 const int* __restrict__ rel,
                                                 const float* __restrict__ norm,
                                                 int* __restrict__ cursor,
                                                 int* __restrict__ epk,
                                                 float* __restrict__ enorm) {
    int e = blockIdx.x * 256 + threadIdx.x;
    int d = dst[e];
    int pos = atomicAdd(&cursor[d], 1);
    epk[pos] = (src[e] << 3) | rel[e];
    enorm[pos] = norm[e];
}

// ---------- layer GEMM (m97 structure, single-buffer, 4 blocks/CU): C = A @ BT^T ----------
// tile 128x128, BK=64, 256 threads; global_load_lds width-16, both-sides XOR swizzle
__global__ __launch_bounds__(256, 4) void k_gemm(const u16* __restrict__ A,
                                                 const u16* __restrict__ BT,
                                                 u16* __restrict__ C,
                                                 int K, int lda, int ldb, int ldc) {
    __shared__ __align__(16) u16 As[128 * 64];
    __shared__ __align__(16) u16 Bs[128 * 64];

    const int t = threadIdx.x;
    // XCD-aware bijective chunk swizzle (nwg = 128*32 = 4096, %8 == 0)
    const int lin = blockIdx.y * 128 + blockIdx.x;
    const int swz = (lin & 7) * 512 + (lin >> 3);
    const int tileM = (swz & 127) * 128;
    const int tileN = (swz >> 7) * 128;

    const int w = t >> 6, l = t & 63;
    const int wr = w >> 1, wc = w & 1;
    const int lo = l & 15, hi = l >> 4;

    const int srow8 = l >> 3;
    const int scol = ((l & 7) ^ srow8) * 8;   // pre-swizzled source 16B-chunk (u16 units)

    f32x4 acc[4][4];
#pragma unroll
    for (int m = 0; m < 4; ++m)
#pragma unroll
        for (int n = 0; n < 4; ++n) acc[m][n] = f32x4{0.f, 0.f, 0.f, 0.f};

    for (int k0 = 0; k0 < K; k0 += 64) {
#pragma unroll
        for (int i = 0; i < 4; ++i) {
            const int rowblk = (w * 4 + i) * 8;            // wave-uniform
            gload16(A + (size_t)(tileM + rowblk + srow8) * lda + k0 + scol, &As[rowblk * 64]);
            gload16(BT + (size_t)(tileN + rowblk + srow8) * ldb + k0 + scol, &Bs[rowblk * 64]);
        }
        __syncthreads();

#pragma unroll
        for (int kk = 0; kk < 2; ++kk) {
            s16x8 af[4], bf[4];
#pragma unroll
            for (int m = 0; m < 4; ++m) {
                int row = wr * 64 + m * 16 + lo;
                int boff = (row * 128 + kk * 64 + hi * 16) ^ ((row & 7) << 4);
                af[m] = *(const s16x8*)((const char*)As + boff);
            }
#pragma unroll
            for (int n = 0; n < 4; ++n) {
                int row = wc * 64 + n * 16 + lo;
                int boff = (row * 128 + kk * 64 + hi * 16) ^ ((row & 7) << 4);
                bf[n] = *(const s16x8*)((const char*)Bs + boff);
            }
#pragma unroll
            for (int m = 0; m < 4; ++m)
#pragma unroll
                for (int n = 0; n < 4; ++n)
                    acc[m][n] = __builtin_amdgcn_mfma_f32_16x16x32_bf16(
                        af[m], bf[n], acc[m][n], 0, 0, 0);
        }
        __syncthreads();
    }

    // epilogue: C/D layout col=lane&15, row=(lane>>4)*4+reg
#pragma unroll
    for (int m = 0; m < 4; ++m)
#pragma unroll
        for (int n = 0; n < 4; ++n) {
            int col = tileN + wc * 64 + n * 16 + lo;
#pragma unroll
            for (int j = 0; j < 4; ++j) {
                int row = tileM + wr * 64 + m * 16 + hi * 4 + j;
                C[(size_t)row * ldc + col] = f2bf(acc[m][n][j]);
            }
        }
}

// ---------- ELMo GEMM: m97 structure, tile 128Mx256N, BK=64, f32 A via global_load_lds ----------
// grid dim3(128, EKSPLIT), 256 threads (4 waves, 2Mx2N of 64x128). LDS: A 32KB f32 + B 32KB bf16
// = 64KB -> 2 blocks/CU. A swizzle: LDS chunk c of row r holds global chunk c^(r&15).
__global__ __launch_bounds__(256, 2) void k_gemm_elmo(const float* __restrict__ A,
                                                      const u16* __restrict__ BT,
                                                      float* __restrict__ Cp) {
    __shared__ __align__(16) float As[128 * 64];   // 128 rows x 64 f32 (256 B/row)
    __shared__ __align__(16) u16   Bs[256 * 64];   // 256 rows x 64 bf16 (128 B/row)

    const int t = threadIdx.x;
    const int tileM = blockIdx.x * 128;
    const int kz = blockIdx.y;
    const int kbeg = kz * (INDIM / EKSPLIT);   // 768 per split, 12 k-steps

    const int w = t >> 6, l = t & 63;
    const int wr = w >> 1, wc = w & 1;
    const int lo = l & 15, hi = l >> 4;

    // A staging: instr i covers rows RA=4*(w*8+i)..+3; lane -> row RA+(l>>4), chunk l&15
    const int ar = l >> 4;                      // row within 4-row group
    // B staging: instr i covers rows RB=8*(w*8+i)..+7; lane -> row RB+(l>>3), chunk l&7
    const int br = l >> 3;
    const int bcol = ((l & 7) ^ br) * 8;        // pre-swizzled source chunk (u16 units)

    f32x4 acc[4][8];
#pragma unroll
    for (int m = 0; m < 4; ++m)
#pragma unroll
        for (int n = 0; n < 8; ++n) acc[m][n] = f32x4{0.f, 0.f, 0.f, 0.f};

    for (int ks = 0; ks < 12; ++ks) {
        const int k0 = kbeg + ks * 64;
        // ---- stage A (8 instr/wave) and B (8 instr/wave) ----
#pragma unroll
        for (int i = 0; i < 8; ++i) {
            const int RA = (w * 8 + i) * 4;                                   // wave-uniform
            const int ca = (l & 15) ^ ((RA & 15) + ar);                       // source chunk
            gload16(A + (size_t)(tileM + RA + ar) * INDIM + k0 + ca * 4, &As[RA * 64]);
            const int RB = (w * 8 + i) * 8;
            gload16(BT + (size_t)(RB + br) * INDIM + k0 + bcol, &Bs[RB * 64]);
        }
        __syncthreads();

        // ---- fragments + MFMA ----
#pragma unroll
        for (int kk = 0; kk < 2; ++kk) {
            s16x8 afr[4], bfr[8];
#pragma unroll
            for (int m = 0; m < 4; ++m) {
                int ra = wr * 64 + m * 16 + lo;
                int x0 = kk * 8 + hi * 2;
                const char* base = (const char*)As + ra * 256;
                f32x4 p = *(const f32x4*)(base + (((x0) ^ (ra & 15)) << 4));
                f32x4 q = *(const f32x4*)(base + (((x0 + 1) ^ (ra & 15)) << 4));
                u32x4 pk = {cvtpk(p[0], p[1]), cvtpk(p[2], p[3]),
                            cvtpk(q[0], q[1]), cvtpk(q[2], q[3])};
                afr[m] = __builtin_bit_cast(s16x8, pk);
            }
#pragma unroll
            for (int n = 0; n < 8; ++n) {
                int rb = wc * 128 + n * 16 + lo;
                int boff = (rb * 128 + kk * 64 + hi * 16) ^ ((rb & 7) << 4);
                bfr[n] = *(const s16x8*)((const char*)Bs + boff);
            }
#pragma unroll
            for (int m = 0; m < 4; ++m)
#pragma unroll
                for (int n = 0; n < 8; ++n)
                    acc[m][n] = __builtin_amdgcn_mfma_f32_16x16x32_bf16(
                        afr[m], bfr[n], acc[m][n], 0, 0, 0);
        }
        __syncthreads();
    }

    // ---- epilogue: f32 partials; C/D layout col=lane&15, row=(lane>>4)*4+reg ----
    float* cp = Cp + (size_t)kz * TOT * 256;
#pragma unroll
    for (int m = 0; m < 4; ++m)
#pragma unroll
        for (int n = 0; n < 8; ++n) {
            int col = wc * 128 + n * 16 + lo;
#pragma unroll
            for (int j = 0; j < 4; ++j) {
                int row = tileM + wr * 64 + m * 16 + hi * 4 + j;
                cp[(size_t)row * 256 + col] = acc[m][n][j];
            }
        }
}

// ---------- ELMo reduce: xb[:, 0:256] = relu(sum_kz Cp + bias) ----------
__global__ __launch_bounds__(256) void k_elmo_reduce(const float* __restrict__ Cp,
                                                     const float* __restrict__ bias,
                                                     u16* __restrict__ xb) {
    int idx = blockIdx.x * 256 + threadIdx.x;   // 16384*256/4 = 1,048,576
    int row = idx >> 6;
    int c4 = (idx & 63) * 4;
    f32x4 s = *(const f32x4*)(Cp + (size_t)row * 256 + c4);
#pragma unroll
    for (int p = 1; p < EKSPLIT; ++p)
        s += *(const f32x4*)(Cp + (size_t)p * TOT * 256 + (size_t)row * 256 + c4);
    f32x4 bv = *(const f32x4*)(bias + c4);
    u16x4 o;
#pragma unroll
    for (int j = 0; j < 4; ++j) o[j] = f2bf(fmaxf(s[j] + bv[j], 0.f));
    *(u16x4*)(xb + (size_t)row * HID + c4) = o;
}

// ---------- aggregation: x_new[d] = relu(b + sum_e norm_e * y[src_e, r_e*512 + :]) ----------
// 256 threads, 2 feats/thread (u32), edge meta in LDS chunks of 64, unroll x16
__global__ __launch_bounds__(256) void k_agg(const u16* __restrict__ y,
                                             const int* __restrict__ rowptr,
                                             const int* __restrict__ epk,
                                             const float* __restrict__ enorm,
                                             const float* __restrict__ bgcn,
                                             u16* __restrict__ xout) {
    __shared__ int   s_epk[64];
    __shared__ float s_nrm[64];
    const int d = blockIdx.x, t = threadIdx.x;
    const u32* yw = (const u32*)y;

    float2 bv = *(const float2*)(bgcn + 2 * t);
    float a0 = bv.x, a1 = bv.y;

    const int beg = rowptr[d], end = rowptr[d + 1];
    for (int base = beg; base < end; base += 64) {
        const int m = min(64, end - base);
        if (t < m) { s_epk[t] = epk[base + t]; s_nrm[t] = enorm[base + t]; }
        __syncthreads();
        int c = 0;
        for (; c + 16 <= m; c += 16) {
            u32 wv[16];
            float nv[16];
#pragma unroll
            for (int q = 0; q < 16; ++q) {
                int k = s_epk[c + q];
                nv[q] = s_nrm[c + q];
                wv[q] = yw[((size_t)(k >> 3) << 11) + ((k & 7) << 8) + t];
            }
#pragma unroll
            for (int q = 0; q < 16; ++q) {
                a0 = fmaf(nv[q], bf2f((u16)wv[q]), a0);
                a1 = fmaf(nv[q], bf2f((u16)(wv[q] >> 16)), a1);
            }
        }
        for (; c + 4 <= m; c += 4) {
            u32 wv[4];
            float nv[4];
#pragma unroll
            for (int q = 0; q < 4; ++q) {
                int k = s_epk[c + q];
                nv[q] = s_nrm[c + q];
                wv[q] = yw[((size_t)(k >> 3) << 11) + ((k & 7) << 8) + t];
            }
#pragma unroll
            for (int q = 0; q < 4; ++q) {
                a0 = fmaf(nv[q], bf2f((u16)wv[q]), a0);
                a1 = fmaf(nv[q], bf2f((u16)(wv[q] >> 16)), a1);
            }
        }
        for (; c < m; ++c) {
            int k0 = s_epk[c];
            float n0 = s_nrm[c];
            u32 w0 = yw[((size_t)(k0 >> 3) << 11) + ((k0 & 7) << 8) + t];
            a0 = fmaf(n0, bf2f((u16)w0), a0);
            a1 = fmaf(n0, bf2f((u16)(w0 >> 16)), a1);
        }
        __syncthreads();
    }
    u32 o = (u32)f2bf(fmaxf(a0, 0.f)) | ((u32)f2bf(fmaxf(a1, 0.f)) << 16);
    ((u32*)xout)[((size_t)d << 8) + t] = o;
}

// ---------- final stage 1: per-(graph, 64-node chunk) feature sums ----------
__global__ __launch_bounds__(512) void k_mean1(const u16* __restrict__ xb,
                                               float* __restrict__ part) {
    int g = blockIdx.x >> 4, chunk = blockIdx.x & 15, t = threadIdx.x;
    const u16* base = xb + ((size_t)g * NODESPER + chunk * 64) * HID;
    float s = 0.f;
    for (int n = 0; n < 64; ++n) s += bf2f(base[(size_t)n * HID + t]);
    part[(size_t)blockIdx.x * HID + t] = s;
}

// ---------- final stage 2: reduce partials -> mean -> logits -> softmax ----------
__global__ __launch_bounds__(512) void k_final2(const float* __restrict__ part,
                                                const float* __restrict__ W_out,
                                                const float* __restrict__ b_out,
                                                float* __restrict__ out) {
    int g = blockIdx.x, t = threadIdx.x;
    __shared__ float mean_s[512];
    __shared__ float lg[128];
    __shared__ float red[128];
    float s = 0.f;
#pragma unroll
    for (int c = 0; c < 16; ++c) s += part[((size_t)g * 16 + c) * HID + t];
    mean_s[t] = s * (1.0f / (float)NODESPER);
    __syncthreads();
    if (t < NOUT) {
        float a = b_out[t];
        for (int k = 0; k < HID; ++k) a = fmaf(mean_s[k], W_out[(size_t)k * NOUT + t], a);
        lg[t] = a;
        red[t] = a;
    }
    __syncthreads();
    for (int off = 64; off > 0; off >>= 1) {
        if (t < off) red[t] = fmaxf(red[t], red[t + off]);
        __syncthreads();
    }
    float mx = red[0];
    __syncthreads();
    if (t < NOUT) { float e = expf(lg[t] - mx); lg[t] = e; red[t] = e; }
    __syncthreads();
    for (int off = 64; off > 0; off >>= 1) {
        if (t < off) red[t] += red[t + off];
        __syncthreads();
    }
    if (t < NOUT) out[(size_t)g * NOUT + t] = lg[t] / red[0];
}

extern "C" void kernel_launch(void* const* d_in, const int* in_sizes, int n_in,
                              void* d_out, int out_size, void* d_ws, size_t ws_size,
                              hipStream_t stream) {
    const float* h      = (const float*)d_in[0];
    const int*   src    = (const int*)d_in[1];
    const int*   dst    = (const int*)d_in[2];
    const int*   rel    = (const int*)d_in[3];
    const float* norm   = (const float*)d_in[4];
    const float* W_elmo = (const float*)d_in[5];
    const float* b_elmo = (const float*)d_in[6];
    const float* comp   = (const float*)d_in[7];
    const float* V      = (const float*)d_in[8];
    const float* b_gcn  = (const float*)d_in[9];
    const float* W_out  = (const float*)d_in[10];
    const float* b_out  = (const float*)d_in[11];
    float* out = (float*)d_out;

    char* ws = (char*)d_ws;
    u16*   xb     = (u16*)(ws + OFF_XB);
    u16*   y      = (u16*)(ws + OFF_Y);
    float* elmoP  = (float*)(ws + OFF_Y);  // dead once elmo_reduce completes
    u16*   wcatT  = (u16*)(ws + OFF_WCT);
    u16*   welmoT = (u16*)(ws + OFF_WET);
    int*   cnt    = (int*)(ws + OFF_CNT);
    int*   rowptr = (int*)(ws + OFF_ROWPTR);
    int*   cursor = (int*)(ws + OFF_CURSOR);
    int*   epk    = (int*)(ws + OFF_EPK);
    float* enorm  = (float*)(ws + OFF_ENORM);
    float* part   = (float*)(ws + OFF_PART);

    // zero x buffer (upper 256 feature dims stay 0 for layer-1 input) and histogram
    hipMemsetAsync(xb, 0, (size_t)TOT * HID * 2, stream);
    hipMemsetAsync(cnt, 0, (size_t)TOT * 4, stream);

    k_prep_wcat<<<dim3(8, 8, 8), 256, 0, stream>>>(comp, V, wcatT);
    k_prep_welmo<<<dim3(48, 4), 256, 0, stream>>>(W_elmo, welmoT);

    k_hist<<<EDGES / 256, 256, 0, stream>>>(dst, cnt);
    k_scan<<<1, 1024, 0, stream>>>(cnt, rowptr, cursor);
    k_scatter<<<EDGES / 256, 256, 0, stream>>>(src, dst, rel, norm, cursor, epk, enorm);

    // ELMo: xb[:, 0:256] = relu(h @ W_elmo + b_elmo)  (M=16384, K=3072 split x4, N=256)
    k_gemm_elmo<<<dim3(128, EKSPLIT), 256, 0, stream>>>(h, welmoT, elmoP);
    k_elmo_reduce<<<4096, 256, 0, stream>>>(elmoP, b_elmo, xb);

    for (int L = 0; L < 3; ++L) {
        // y = xb @ Wcat   (M=16384, N=4096; K=256 for layer 1 — xb cols 256.. are zero)
        const int Keff = (L == 0) ? 256 : 512;
        k_gemm<<<dim3(128, 32), 256, 0, stream>>>(xb, wcatT, y, Keff, HID, HID,
                                                  NRELS * HID);
        // xb = relu(b_gcn + segment_sum(norm * y[src, r]))
        k_agg<<<TOT, 256, 0, stream>>>(y, rowptr, epk, enorm, b_gcn, xb);
    }

    k_mean1<<<NGRAPH * 16, 512, 0, stream>>>(xb, part);
    k_final2<<<NGRAPH, 512, 0, stream>>>(part, W_out, b_out, out);
}